// Round 1
// baseline (678.268 us; speedup 1.0000x reference)
//
#include <hip/hip_runtime.h>

// Cost-volume construction:
//   out[b][c2][d][h][w] = (c2 <  C) ? x[b][c2  ][h][w  ] * (w>=d)
//                       : (c2 >= C) ? y[b][c2-C][h][w-d] * (w>=d)   (0 when w<d)
// B=2, C=32, D=64, H=80, W=240. Output (B, 2C, D, H, W) fp32 = 629 MB -> write-BW bound.

#define BB 2
#define CC 32
#define DD 64
#define HH 80
#define WW 240
#define W4 (WW / 4)   // 60 float4 per row; rows are 960 B so 16B-aligned

__global__ __launch_bounds__(256) void costvol_kernel(const float* __restrict__ x,
                                                      const float* __restrict__ y,
                                                      float* __restrict__ out,
                                                      unsigned nq) {
    unsigned q = blockIdx.x * 256u + threadIdx.x;
    if (q >= nq) return;

    // out quad index q = (((b*2C + c2)*D + d)*H + h)*W4 + qw
    unsigned qw = q % W4;
    unsigned t  = q / W4;
    unsigned h  = t % HH;        t /= HH;
    unsigned d  = t % DD;        t /= DD;
    unsigned c2 = t % (2 * CC);
    unsigned b  = t / (2 * CC);

    unsigned w0 = qw * 4u;
    float4 v;

    if (c2 < CC) {
        // left: aligned float4 load of x row, masked by (w >= d)
        const float4* xr = (const float4*)(x + (size_t)((b * CC + c2) * HH + h) * WW);
        v = xr[qw];
        if (w0 + 0 < d) v.x = 0.f;
        if (w0 + 1 < d) v.y = 0.f;
        if (w0 + 2 < d) v.z = 0.f;
        if (w0 + 3 < d) v.w = 0.f;
    } else {
        // right: shifted y row (unaligned by d) -> scalar loads, L1/L2-served
        unsigned c = c2 - CC;
        const float* yr = y + (size_t)((b * CC + c) * HH + h) * WW;
        v.x = (w0 + 0 >= d) ? yr[w0 + 0 - d] : 0.f;
        v.y = (w0 + 1 >= d) ? yr[w0 + 1 - d] : 0.f;
        v.z = (w0 + 2 >= d) ? yr[w0 + 2 - d] : 0.f;
        v.w = (w0 + 3 >= d) ? yr[w0 + 3 - d] : 0.f;
    }

    ((float4*)out)[q] = v;   // coalesced: wave writes 1 KiB contiguous
}

extern "C" void kernel_launch(void* const* d_in, const int* in_sizes, int n_in,
                              void* d_out, int out_size, void* d_ws, size_t ws_size,
                              hipStream_t stream) {
    const float* x = (const float*)d_in[0];
    const float* y = (const float*)d_in[1];
    float* out     = (float*)d_out;

    unsigned nq = (unsigned)(out_size / 4);          // 39,321,600 quads
    dim3 grid((nq + 255u) / 256u), block(256);
    hipLaunchKernelGGL(costvol_kernel, grid, block, 0, stream, x, y, out, nq);
}

// Round 2
// 653.266 us; speedup vs baseline: 1.0383x; 1.0383x over previous
//
#include <hip/hip_runtime.h>

// Cost-volume construction, out (B=2, 2C=64, D=64, H=80, W=240) fp32 = 629 MB.
//   out[b][c   ][d][h][w] = x[b][c][h][w]   * (w>=d)
//   out[b][32+c][d][h][w] = y[b][c][h][w-d] * (w>=d)
//
// Strategy: one block per (b,c,h) row. Stage x-row + y-row in LDS (y-row with a
// 64-float zero pad on the left so w<d reads return 0 with no masking), then
// write all 128 output rows (2 halves x 64 d) as coalesced float4 stores.
// Global reads: 2 rows/block (~10 MB total, cache-served). Pure store-bound.

#define W4    60u       // float4 per row (W=240)
#define CH4   307200u   // D*H*W4 = 64*80*60  float4 per output channel
#define D4    4800u     // H*W4   = 80*60     float4 per d-slice

__global__ __launch_bounds__(256) void costvol_kernel(const float* __restrict__ x,
                                                      const float* __restrict__ y,
                                                      float* __restrict__ out) {
    __shared__ float xs[240];
    __shared__ float ysbuf[64 + 240];   // [0,64) = zeros, [64,304) = y row

    const unsigned t  = threadIdx.x;
    const unsigned blk = blockIdx.x;         // (b*32 + c)*80 + h
    const unsigned h  = blk % 80u;
    const unsigned bc = blk / 80u;           // b*32 + c
    const unsigned c  = bc % 32u;
    const unsigned b  = bc / 32u;

    const float4* xrow = (const float4*)(x + (size_t)blk * 240u);
    const float4* yrow = (const float4*)(y + (size_t)blk * 240u);

    // Cooperative staging: 16 quads of zero pad, 60 quads of y, 60 quads of x.
    if (t < 16u)                 ((float4*)ysbuf)[t]       = make_float4(0.f, 0.f, 0.f, 0.f);
    else if (t < 76u)            ((float4*)ysbuf)[t]       = yrow[t - 16u];
    if (t >= 128u && t < 188u)   ((float4*)xs)[t - 128u]   = xrow[t - 128u];
    __syncthreads();

    const float* ys = ysbuf + 64;            // ys[s] valid for s >= -63
    float4* out4 = (float4*)out;
    const unsigned baseL = (b * 64u + c)       * CH4 + h * W4;
    const unsigned baseR = (b * 64u + 32u + c) * CH4 + h * W4;

    // Left half: 64 d x 60 quads = 3840 quads, 15 iterations of 256 threads.
    #pragma unroll
    for (unsigned it = 0; it < 15u; ++it) {
        unsigned i  = it * 256u + t;         // [0, 3840)
        unsigned d  = i / 60u;
        unsigned qw = i - d * 60u;
        float4 v = ((const float4*)xs)[qw];  // dense b128, conflict-free
        int w0 = 4 * (int)qw, dd = (int)d;
        if (w0 + 0 < dd) v.x = 0.f;
        if (w0 + 1 < dd) v.y = 0.f;
        if (w0 + 2 < dd) v.z = 0.f;
        if (w0 + 3 < dd) v.w = 0.f;
        out4[baseL + d * D4 + qw] = v;
    }

    // Right half: shifted y, mask is free via the zero pad.
    #pragma unroll
    for (unsigned it = 0; it < 15u; ++it) {
        unsigned i  = it * 256u + t;
        unsigned d  = i / 60u;
        unsigned qw = i - d * 60u;
        int s = 4 * (int)qw - (int)d;        // in [-63, 236]
        float4 v;
        v.x = ys[s + 0];
        v.y = ys[s + 1];
        v.z = ys[s + 2];
        v.w = ys[s + 3];
        out4[baseR + d * D4 + qw] = v;
    }
}

extern "C" void kernel_launch(void* const* d_in, const int* in_sizes, int n_in,
                              void* d_out, int out_size, void* d_ws, size_t ws_size,
                              hipStream_t stream) {
    const float* x = (const float*)d_in[0];
    const float* y = (const float*)d_in[1];
    float* out     = (float*)d_out;

    dim3 grid(2u * 32u * 80u), block(256);   // one block per (b,c,h) row
    hipLaunchKernelGGL(costvol_kernel, grid, block, 0, stream, x, y, out);
}